// Round 1
// baseline (186.509 us; speedup 1.0000x reference)
//
#include <hip/hip_runtime.h>
#include <hip/hip_bf16.h>
#include <stdint.h>

#define GAMMA 0.002f
#define MDIM 4096
#define NDIM 8192
#define KDIM 512
#define BM 128
#define BN 128
#define BK 32

typedef short v8s __attribute__((ext_vector_type(8)));
typedef float v4f __attribute__((ext_vector_type(4)));

__device__ __forceinline__ unsigned short f32_to_bf16_rne(float f) {
    union { float f; uint32_t u; } v; v.f = f;
    uint32_t u = v.u;
    return (unsigned short)((u + 0x7fffu + ((u >> 16) & 1u)) >> 16);
}

__device__ __forceinline__ void gl_lds16(const void* g, void* l) {
    __builtin_amdgcn_global_load_lds(
        (const __attribute__((address_space(1))) uint32_t*)g,
        (__attribute__((address_space(3))) uint32_t*)l, 16, 0, 0);
}

// One block per row: convert 512 fp32 -> bf16 (RNE) and emit -gamma*sum(x^2) in fp32.
__global__ __launch_bounds__(256) void convert_rows(
    const float* __restrict__ in, unsigned short* __restrict__ outb,
    float* __restrict__ neg_g_sq) {
    int row = blockIdx.x;
    const float* src = in + (size_t)row * KDIM;
    unsigned short* dst = outb + (size_t)row * KDIM;
    int t = threadIdx.x;
    float2 f = ((const float2*)src)[t];
    ushort2 b;
    b.x = f32_to_bf16_rne(f.x);
    b.y = f32_to_bf16_rne(f.y);
    ((ushort2*)dst)[t] = b;
    float s = f.x * f.x + f.y * f.y;
    #pragma unroll
    for (int off = 32; off > 0; off >>= 1) s += __shfl_down(s, off, 64);
    __shared__ float red[4];
    if ((t & 63) == 0) red[t >> 6] = s;
    __syncthreads();
    if (t == 0) neg_g_sq[row] = -GAMMA * (red[0] + red[1] + red[2] + red[3]);
}

// C[m,n] = exp(arow[m] + ccol[n] + 2*gamma*dot(x[m], sv[n]))
__global__ __launch_bounds__(256) void rbf_gemm(
    const unsigned short* __restrict__ A,   // [4096,512] bf16
    const unsigned short* __restrict__ B,   // [8192,512] bf16
    const float* __restrict__ arow,         // [4096]  = -g*||x||^2
    const float* __restrict__ ccol,         // [8192]  = -g*||sv||^2
    float* __restrict__ out) {

    __shared__ __align__(16) unsigned short sA[BM * BK];  // 8 KiB
    __shared__ __align__(16) unsigned short sB[BN * BK];  // 8 KiB

    const int tid  = threadIdx.x;
    const int lane = tid & 63;
    const int wave = tid >> 6;          // 0..3
    const int wm   = wave >> 1;         // 0..1
    const int wn   = wave & 1;          // 0..1
    const int row0 = blockIdx.y * BM;   // 0..4095
    const int col0 = blockIdx.x * BN;   // 0..8191

    // staging: thread covers row (tid>>2) (+64 for 2nd issue), 8 elems at col (tid&3)*8
    const unsigned short* aptr = A + (size_t)(row0 + (tid >> 2)) * KDIM + (tid & 3) * 8;
    const unsigned short* bptr = B + (size_t)(col0 + (tid >> 2)) * KDIM + (tid & 3) * 8;
    unsigned short* sAp = &sA[tid * 8];   // byte offset tid*16
    unsigned short* sBp = &sB[tid * 8];

    v4f acc[4][4];
    #pragma unroll
    for (int i = 0; i < 4; i++)
        #pragma unroll
        for (int j = 0; j < 4; j++) acc[i][j] = (v4f)0.0f;

    const int q    = lane >> 4;   // 0..3  -> k chunk q*8
    const int r16  = lane & 15;   // row within 16-tile (A) / col row (B)

    for (int k0 = 0; k0 < KDIM; k0 += BK) {
        gl_lds16(aptr + k0, sAp);
        gl_lds16(aptr + (size_t)64 * KDIM + k0, sAp + 2048);
        gl_lds16(bptr + k0, sBp);
        gl_lds16(bptr + (size_t)64 * KDIM + k0, sBp + 2048);
        __syncthreads();   // compiler emits vmcnt(0) drain before barrier

        v8s afrag[4], bfrag[4];
        #pragma unroll
        for (int i = 0; i < 4; i++) {
            afrag[i] = *(const v8s*)&sA[(wm * 64 + i * 16 + r16) * BK + q * 8];
            bfrag[i] = *(const v8s*)&sB[(wn * 64 + i * 16 + r16) * BK + q * 8];
        }
        #pragma unroll
        for (int i = 0; i < 4; i++)
            #pragma unroll
            for (int j = 0; j < 4; j++)
                acc[i][j] = __builtin_amdgcn_mfma_f32_16x16x32_bf16(
                    afrag[i], bfrag[j], acc[i][j], 0, 0, 0);
        __syncthreads();   // protect LDS before next-iter staging
    }

    // stage per-block row/col bias terms into (now free) LDS
    float* fA = (float*)sA;   // 128 floats
    float* fC = (float*)sB;   // 128 floats
    if (tid < 128) fA[tid] = arow[row0 + tid];
    else           fC[tid - 128] = ccol[col0 + tid - 128];
    __syncthreads();

    const float tg = 2.0f * GAMMA;
    #pragma unroll
    for (int i = 0; i < 4; i++) {
        #pragma unroll
        for (int j = 0; j < 4; j++) {
            const int rbase = wm * 64 + i * 16 + q * 4;
            const int cl    = wn * 64 + j * 16 + r16;
            const float cc  = fC[cl];
            float* gp = out + (size_t)(row0 + rbase) * NDIM + (col0 + cl);
            #pragma unroll
            for (int v = 0; v < 4; v++) {
                gp[(size_t)v * NDIM] = __expf(fmaf(tg, acc[i][j][v], fA[rbase + v] + cc));
            }
        }
    }
}

extern "C" void kernel_launch(void* const* d_in, const int* in_sizes, int n_in,
                              void* d_out, int out_size, void* d_ws, size_t ws_size,
                              hipStream_t stream) {
    const float* x  = (const float*)d_in[0];   // [4096,512]
    const float* sv = (const float*)d_in[1];   // [8192,512]
    float* out = (float*)d_out;

    // ws layout: xb (4 MiB) | svb (8 MiB) | arow (16 KiB) | ccol (32 KiB)
    unsigned short* xb  = (unsigned short*)d_ws;
    unsigned short* svb = xb + (size_t)MDIM * KDIM;
    float* arow = (float*)(svb + (size_t)NDIM * KDIM);
    float* ccol = arow + MDIM;

    hipLaunchKernelGGL(convert_rows, dim3(MDIM), dim3(256), 0, stream, x, xb, arow);
    hipLaunchKernelGGL(convert_rows, dim3(NDIM), dim3(256), 0, stream, sv, svb, ccol);
    hipLaunchKernelGGL(rbf_gemm, dim3(NDIM / BN, MDIM / BM), dim3(256), 0, stream,
                       xb, svb, arow, ccol, out);
}